// Round 9
// baseline (451.821 us; speedup 1.0000x reference)
//
#include <hip/hip_runtime.h>
#include <cstdint>
#include <cstddef>

// Problem constants (from reference)
#define TOKENS 2048
#define IN_F   4096
#define OUT_F  11008
#define W_BIT  4
#define RANK   16
#define QWB    (OUT_F * IN_F / 8)   // 5,636,096 int32 "bytes" per bit-plane

typedef unsigned short ushort_t;
typedef __attribute__((ext_vector_type(8))) short   short8;   // 8 bf16 = 4 VGPRs (MFMA A/B frag)
typedef __attribute__((ext_vector_type(4))) float   floatx4;  // MFMA C/D frag

__device__ __forceinline__ ushort_t f2bf(float f) {
  union { float f; uint32_t u; } c; c.f = f;
  uint32_t r = c.u + 0x7FFFu + ((c.u >> 16) & 1u);  // RNE
  return (ushort_t)(r >> 16);
}

// async global->LDS, 16B per lane; lds pointer must be wave-uniform base (HW adds lane*16)
__device__ __forceinline__ void gl_lds16(const void* g, void* l) {
  __builtin_amdgcn_global_load_lds(
      (const __attribute__((address_space(1))) uint32_t*)g,
      (__attribute__((address_space(3))) uint32_t*)l, 16, 0, 0);
}

// ---------------- phase 0a: x fp32 -> bf16 ----------------
__global__ __launch_bounds__(256) void k_cvt_x(const float* __restrict__ x,
                                               ushort_t* __restrict__ xb) {
  int idx = blockIdx.x * 256 + threadIdx.x;
  float4 v = ((const float4*)x)[idx];
  ushort4 r;
  r.x = f2bf(v.x); r.y = f2bf(v.y); r.z = f2bf(v.z); r.w = f2bf(v.w);
  ((ushort4*)xb)[idx] = r;
}

// ---------------- phase 0b: u -> bf16 (same layout), vt -> bf16 transposed ----------------
#define N_U  (W_BIT * OUT_F * RANK)   // 704512
#define N_VT (W_BIT * RANK * IN_F)    // 262144
__global__ __launch_bounds__(256) void k_prep_uv(const float* __restrict__ u,
                                                 const float* __restrict__ vt,
                                                 ushort_t* __restrict__ ub,
                                                 ushort_t* __restrict__ vtT) {
  int idx = blockIdx.x * 256 + threadIdx.x;
  if (idx < N_U) {
    ub[idx] = f2bf(u[idx]);
  } else {
    int e = idx - N_U;                 // [0, N_VT)
    int b = e >> 16;                   // RANK*IN_F = 65536
    int r = e & 65535;
    int k = r >> 12;                   // IN_F = 4096
    int i = r & 4095;
    vtT[((size_t)b * IN_F + i) * RANK + k] = f2bf(vt[e]);
  }
}

// ---------------- phase 1: build w (bf16): MFMA product + LDS-staged sign apply ----
// Round-0 version, verbatim (best measured). Do NOT edit blind.
__global__ __launch_bounds__(256) void k_build_w(const int* __restrict__ qw,
                                                 const ushort_t* __restrict__ ub,
                                                 const ushort_t* __restrict__ vtT,
                                                 ushort_t* __restrict__ w) {
  __shared__ int qs[W_BIT * 128 * 20];  // 40 KB
  const int tid = threadIdx.x;
  const int ob = blockIdx.x / (IN_F / 128);
  const int ib = blockIdx.x % (IN_F / 128);
  const int o0 = ob * 128, i0 = ib * 128;
  const int lane = tid & 63, wv = tid >> 6;
  const int wm = (wv >> 1) * 64, wn = (wv & 1) * 64;
  const int l16 = lane & 15, q = lane >> 4;
  const bool qlo = (q < 2);
  const int koff = (q & 1) * 8;        // valid k-halves for q=0,1; q>=2 zeroed
  const short8 zf = (short8)0;

  // stage qw tile: 4 planes x 128 rows x 16 ints; 2048 int4 chunks, 8/thread, coalesced
  #pragma unroll
  for (int n = 0; n < 8; ++n) {
    int c = n * 256 + tid;             // [0, 2048)
    int b = c >> 9, rem = c & 511;
    int row = rem >> 2, part = rem & 3;
    int4 v = *(const int4*)(qw + (size_t)b * QWB +
                            (size_t)(o0 + row) * (IN_F / 8) + (i0 >> 3) + part * 4);
    *(int4*)&qs[(b * 128 + row) * 20 + part * 4] = v;
  }

  floatx4 acc[16];
  #pragma unroll
  for (int i = 0; i < 16; ++i) acc[i] = (floatx4){0.f, 0.f, 0.f, 0.f};

  const int qc_base = (wn >> 3) + (l16 >> 3);  // LDS int col for this lane (+ni*2)
  const int bit = l16 & 7;

  __syncthreads();

  #pragma unroll
  for (int b = 0; b < W_BIT; ++b) {
    short8 af[4], bfr[4];
    #pragma unroll
    for (int mi = 0; mi < 4; ++mi) {
      short8 v = *(const short8*)&ub[((size_t)b * OUT_F + o0 + wm + mi * 16 + l16) * RANK + koff];
      af[mi] = qlo ? v : zf;
    }
    #pragma unroll
    for (int ni = 0; ni < 4; ++ni) {
      short8 v = *(const short8*)&vtT[((size_t)b * IN_F + i0 + wn + ni * 16 + l16) * RANK + koff];
      bfr[ni] = qlo ? v : zf;
    }

    #pragma unroll
    for (int mi = 0; mi < 4; ++mi) {
      floatx4 p[4];
      #pragma unroll
      for (int ni = 0; ni < 4; ++ni)
        p[ni] = __builtin_amdgcn_mfma_f32_16x16x32_bf16(
            af[mi], bfr[ni], (floatx4){0.f, 0.f, 0.f, 0.f}, 0, 0, 0);
      // C layout: col = l16, row = q*4 + v4  [verified m89/m91]
      #pragma unroll
      for (int v4 = 0; v4 < 4; ++v4) {
        const int o_loc = wm + mi * 16 + q * 4 + v4;
        const int* qrow = &qs[(b * 128 + o_loc) * 20];
        #pragma unroll
        for (int ni = 0; ni < 4; ++ni) {
          int qv = qrow[qc_base + ni * 2];
          float pv = p[ni][v4];
          acc[mi * 4 + ni][v4] += ((qv >> bit) & 1) ? pv : -pv;
        }
      }
    }
  }

  // store: 16 consecutive lanes (l16) write 16 consecutive bf16 -> 32B segments
  #pragma unroll
  for (int mi = 0; mi < 4; ++mi) {
    #pragma unroll
    for (int v4 = 0; v4 < 4; ++v4) {
      const int o = o0 + wm + mi * 16 + q * 4 + v4;
      #pragma unroll
      for (int ni = 0; ni < 4; ++ni)
        w[(size_t)o * IN_F + i0 + wn + ni * 16 + l16] = f2bf(acc[mi * 4 + ni][v4]);
    }
  }
}

// ---------------- phase 2: y = x @ w^T  (bf16 MFMA, 256x256 8-phase dual-barrier) ------
// M=2048, N=11008, K=4096. BM=BN=256, BK=32. 512 threads = 8 waves (2Mx4N),
// wave tile 128x64 = 8x4 frags of 16x16x32; 32 MFMA per wave per K-tile.
//
// m201-template port (the only plain-HIP structure measured >900 TF: 1563 TF @4k,
// MfmaUtil 62%). Key mechanism my single-barrier rings lacked: TWO barriers around
// each 16-MFMA cluster + ONE counted vmcnt per K-tile placed at the tile's LAST
// phase, so the barrier that publishes tile t+1 sits between tile t's ds_reads and
// tile t+1's ds_reads (no publication race, loads span phases, never drain).
//
// Per K-tile t (2 phases):
//  P0: ds_read A m0-3 + B n0-3 (8 b128, slot t%3); stage A-volleys(t+2) (2 gl_lds16);
//      barrier; setprio(1) 16 MFMA (acc rows 0-3) setprio(0); barrier
//  P1: ds_read A m4-7 (4 b128); stage B-volleys(t+2); s_waitcnt vmcnt(4);
//      barrier [publishes tile t+1]; setprio(1) 16 MFMA (rows 4-7) setprio(0); barrier
// Ledger: 4 loads/thread/tile (A r0-127, A r128-255, B r0-127, B r128-255), 2/phase.
// vmcnt(4) at (t,1) keeps t+2's 4 newest in flight, completes t+1 -> published by
// the following barrier. Prologue: stage t0,t1 (8 loads), vmcnt(4), barrier.
// Tail: t=126 no stage + vmcnt(0) at P1 (publishes 127); t=127 no stage.
// Slot-reuse: write slot (t+2)%3 = (t-1)%3; its readers' values were consumed by
// MFMAs before the trailing barrier of (t-1,P1); staging issues after it.
// Residency of reads-before-barrier: slot t was published at (t-1,P1)'s barrier,
// strictly before any phase-(t,P0) ds_read issues. No race.
// Swizzle: proven map (0 conflicts r1-r8): dest chunk = tid&3 linear, src k-chunk
// = (tid&3)^((tid>>3)&3); read chunk sQ = q^((l16>>1)&3); row offsets {128} and
// frag offsets {16,128} all ≡ 0 mod 8 -> terms invariant.
// Grid 344 = 8*43 (bijective XCD swizzle); 67% tail efficiency accepted -- this
// structure's measured per-CU rate beats the ~900 TF ring family by ~1.7x.
// __launch_bounds__(512,2): 256-reg cap vs ~200 est. need (margin 56; spill check
// = WRITE_SIZE >> 88MB next round).
#define NSTEP (IN_F / 32)   // 128 K-tiles
#define SLOT  32768         // A 16KB + B 16KB
#define NSLOT 3
__global__ __launch_bounds__(512, 2) void k_gemm_bt(const ushort_t* __restrict__ A,  // [2048][4096]
                                                    const ushort_t* __restrict__ B,  // [11008][4096]
                                                    float* __restrict__ C) {         // [2048][11008]
  __shared__ __attribute__((aligned(16))) char lds[NSLOT * SLOT];  // 96 KB
  const int tid = threadIdx.x;
  const int wg = (blockIdx.x & 7) * 43 + (blockIdx.x >> 3);  // bijective XCD swizzle (344=8*43)
  const int bm = wg & 7;     // 8 M-tiles of 256
  const int bn = wg >> 3;    // 43 N-tiles of 256
  const int lane = tid & 63, wv = tid >> 6;
  const int wm = wv >> 2, wn = wv & 3;      // wave grid 2(M) x 4(N), wave tile 128x64
  const int l16 = lane & 15, q = lane >> 4;
  const int sQ = q ^ ((l16 >> 1) & 3);      // read-side swizzled 16B-chunk slot (thread const)

  const size_t ar = (size_t)bm * 256, br = (size_t)bn * 256;
  // staging: A/B tiles 256x32; volley = 512 thr x 16B = 8KB = 128 rows.
  // chunk tid: row = tid>>2 (+128 for volley 1), dest16 = tid&3,
  // src k-chunk = (tid&3) ^ ((row>>1)&3)  (row+128 invariant).
  const int qsrc = (tid & 3) ^ ((tid >> 3) & 3);
  const ushort_t* Ae = A + (ar + (tid >> 2)) * IN_F + qsrc * 8;
  const ushort_t* Be = B + (br + (tid >> 2)) * IN_F + qsrc * 8;
  const int ldsoff = (tid & 448) * 16;      // wave-uniform dest base (HW adds lane*16)
  const int aFrag = (wm * 128 + l16) * 64 + sQ * 16;  // byte off in A region (+mi*1024, mi 0..7)
  const int bFrag = (wn * 64 + l16) * 64 + sQ * 16;   // byte off in B region (+ni*1024)

  floatx4 acc[8][4];
  #pragma unroll
  for (int mi = 0; mi < 8; ++mi)
    #pragma unroll
    for (int ni = 0; ni < 4; ++ni) acc[mi][ni] = (floatx4){0.f, 0.f, 0.f, 0.f};

  short8 af0[4], af1[4], bf[4];
  int sRd = 0, sWr = 2 * SLOT;   // slot byte offsets: read tile t, write tile t+2

#define STAGE_A(kt, off) do {                                                \
    const size_t _k0 = (size_t)(kt) * 32;                                    \
    char* _d = lds + (off) + ldsoff;                                         \
    gl_lds16(Ae + _k0,                _d);                                   \
    gl_lds16(Ae + 128 * IN_F + _k0,   _d + 8192);                            \
  } while (0)

#define STAGE_B(kt, off) do {                                                \
    const size_t _k0 = (size_t)(kt) * 32;                                    \
    char* _d = lds + (off) + 16384 + ldsoff;                                 \
    gl_lds16(Be + _k0,                _d);                                   \
    gl_lds16(Be + 128 * IN_F + _k0,   _d + 8192);                            \
  } while (0)

#define PHASE0(t_, DO_STAGE) do {                                            \
    {                                                                        \
      const char* _ab = lds + sRd;                                           \
      const char* _bb = _ab + 16384;                                         \
      _Pragma("unroll") for (int mi = 0; mi < 4; ++mi)                       \
        af0[mi] = *(const short8*)(_ab + aFrag + mi * 1024);                 \
      _Pragma("unroll") for (int ni = 0; ni < 4; ++ni)                       \
        bf[ni] = *(const short8*)(_bb + bFrag + ni * 1024);                  \
    }                                                                        \
    if (DO_STAGE) STAGE_A((t_) + 2, sWr);                                    \
    asm volatile("" ::: "memory");                                           \
    __builtin_amdgcn_s_barrier();                                            \
    asm volatile("" ::: "memory");                                           \
    __builtin_amdgcn_s_setprio(1);                                           \
    _Pragma("unroll") for (int mi = 0; mi < 4; ++mi)                         \
      _Pragma("unroll") for (int ni = 0; ni < 4; ++ni)                       \
        acc[mi][ni] = __builtin_amdgcn_mfma_f32_16x16x32_bf16(               \
            af0[mi], bf[ni], acc[mi][ni], 0, 0, 0);                          \
    __builtin_amdgcn_s_setprio(0);                                           \
    asm volatile("" ::: "memory");                                           \
    __builtin_amdgcn_s_barrier();                                            \
    asm volatile("" ::: "memory");                                           \
  } while (0)

#define PHASE1(t_, DO_STAGE, VM) do {                                        \
    {                                                                        \
      const char* _ab = lds + sRd;                                           \
      _Pragma("unroll") for (int mi = 0; mi < 4; ++mi)                       \
        af1[mi] = *(const short8*)(_ab + aFrag + (4 + mi) * 1024);           \
    }                                                                        \
    if (DO_STAGE) STAGE_B((t_) + 2, sWr);                                    \
    asm volatile(VM ::: "memory");       /* publish tile t_+1 after barrier */\
    __builtin_amdgcn_s_barrier();                                            \
    asm volatile("" ::: "memory");                                           \
    __builtin_amdgcn_s_setprio(1);                                           \
    _Pragma("unroll") for (int mi = 0; mi < 4; ++mi)                         \
      _Pragma("unroll") for (int ni = 0; ni < 4; ++ni)                       \
        acc[4 + mi][ni] = __builtin_amdgcn_mfma_f32_16x16x32_bf16(           \
            af1[mi], bf[ni], acc[4 + mi][ni], 0, 0, 0);                      \
    __builtin_amdgcn_s_setprio(0);                                           \
    asm volatile("" ::: "memory");                                           \
    __builtin_amdgcn_s_barrier();                                            \
    asm volatile("" ::: "memory");                                           \
    sRd += SLOT; if (sRd == NSLOT * SLOT) sRd = 0;                           \
    sWr += SLOT; if (sWr == NSLOT * SLOT) sWr = 0;                           \
  } while (0)

  // prologue: stage tiles 0,1 (8 loads: A0,B0,A1,B1); wait tile 0 (keep tile 1's 4)
  STAGE_A(0, 0); STAGE_B(0, 0);
  STAGE_A(1, SLOT); STAGE_B(1, SLOT);
  asm volatile("s_waitcnt vmcnt(4)" ::: "memory");
  __builtin_amdgcn_s_barrier();
  asm volatile("" ::: "memory");

  // steady: tiles 0..125 stage t+2 (covers 2..127); vmcnt(4) once per tile at P1
  for (int t = 0; t < NSTEP - 2; ++t) {
    PHASE0(t, true);
    PHASE1(t, true, "s_waitcnt vmcnt(4)");
  }
  // tail: 126 publishes 127 with vmcnt(0); 127 computes last tile
  PHASE0(NSTEP - 2, false);
  PHASE1(NSTEP - 2, false, "s_waitcnt vmcnt(0)");
  PHASE0(NSTEP - 1, false);
  PHASE1(NSTEP - 1, false, "s_waitcnt vmcnt(0)");

#undef STAGE_A
#undef STAGE_B
#undef PHASE0
#undef PHASE1

  // C/D layout: col = lane&15, row = (lane>>4)*4 + reg  [verified m89/m91]
  #pragma unroll
  for (int mi = 0; mi < 8; ++mi) {
    #pragma unroll
    for (int ni = 0; ni < 4; ++ni) {
      #pragma unroll
      for (int v = 0; v < 4; ++v) {
        int r = bm * 256 + wm * 128 + mi * 16 + q * 4 + v;
        int c = bn * 256 + wn * 64 + ni * 16 + l16;
        C[(size_t)r * OUT_F + c] = acc[mi][ni][v];
      }
    }
  }
}

extern "C" void kernel_launch(void* const* d_in, const int* in_sizes, int n_in,
                              void* d_out, int out_size, void* d_ws, size_t ws_size,
                              hipStream_t stream) {
  (void)in_sizes; (void)n_in; (void)out_size; (void)ws_size;
  const float* x  = (const float*)d_in[0];
  const int*   qw = (const int*)d_in[1];
  const float* u  = (const float*)d_in[2];
  const float* vt = (const float*)d_in[3];
  float* out = (float*)d_out;

  // workspace layout (bytes):
  //   xb  @ 0         : 2048*4096*2   = 16,777,216
  //   wb  @ 16.0 MB   : 11008*4096*2  = 90,177,536
  //   ub  @ 102.0 MB  : 4*11008*16*2  = 1,409,024
  //   vtT @ 103.3 MB  : 4*4096*16*2   = 524,288     (total ~103.8 MiB)
  char* wsp = (char*)d_ws;
  ushort_t* xb  = (ushort_t*)wsp;
  ushort_t* wb  = (ushort_t*)(wsp + (size_t)TOKENS * IN_F * 2);
  ushort_t* ubf = (ushort_t*)(wsp + (size_t)TOKENS * IN_F * 2 + (size_t)OUT_F * IN_F * 2);
  ushort_t* vtT = (ushort_t*)(wsp + (size_t)TOKENS * IN_F * 2 + (size_t)OUT_F * IN_F * 2 +
                              (size_t)N_U * 2);

  k_cvt_x<<<TOKENS * IN_F / 1024, 256, 0, stream>>>(x, xb);
  k_prep_uv<<<(N_U + N_VT) / 256, 256, 0, stream>>>(u, vt, ubf, vtT);
  k_build_w<<<(OUT_F / 128) * (IN_F / 128), 256, 0, stream>>>(qw, ubf, vtT, wb);
  k_gemm_bt<<<8 * (OUT_F / 256), 512, 0, stream>>>(xb, wb, out);
}